// Round 3
// baseline (283.472 us; speedup 1.0000x reference)
//
#include <hip/hip_runtime.h>

// Problem constants (reference: B=64, T=512, D=1024, U=128)
#define TT 512
#define DD 1024
#define UU 128
#define MM 32768            // B*T rows
#define BK 64
#define NCHUNK 16
#define LDA 68              // pad +4 elems (8 B): frag b128 reads ~2-way (free)
#define LDB 68

typedef short short8 __attribute__((ext_vector_type(8)));   // 8 bf16 (MFMA A/B frag)
typedef float f32x4 __attribute__((ext_vector_type(4)));    // MFMA C/D frag

// fp32 -> bf16 round-to-nearest-even
__device__ __forceinline__ unsigned short f2bf(float f) {
    union { float f; unsigned u; } v; v.f = f;
    unsigned u = v.u;
    return (unsigned short)((u + 0x7fffu + ((u >> 16) & 1u)) >> 16);
}

// ---------------------------------------------------------------------------
// Kernel 0: W[k][n] fp32 (1024x128) -> ws bf16, transposed+chunked:
// wt[kc*8192 + n*64 + k'] = bf16(W[kc*64+k'][n]).   (verified R1/R2)
// ---------------------------------------------------------------------------
__global__ __launch_bounds__(256) void wprep_kernel(const float* __restrict__ w,
                                                    unsigned short* __restrict__ wt) {
    int tg = blockIdx.x * 256 + threadIdx.x;   // 0..16383
    int kg = tg & 7;
    int n  = (tg >> 3) & 127;
    int kc = tg >> 10;
    union { unsigned short s[8]; uint4 v; } o;
#pragma unroll
    for (int j = 0; j < 8; ++j) {
        int k = kc * 64 + kg * 8 + j;
        o.s[j] = f2bf(w[k * 128 + n]);
    }
    *(uint4*)(wt + tg * 8) = o.v;
}

// ---------------------------------------------------------------------------
// Kernel 1: 32(M) x 128(N) per block, 256 thr = 4 waves, each wave 16x64.
// Coalesced global->reg prefetch (ping-pong, cross-barrier) -> LDS -> MFMA.
// 1024 blocks = 4 blocks/CU; LDS 21.7 KB single-buffered.
// ---------------------------------------------------------------------------
__global__ __launch_bounds__(256, 4) void crf_energy_kernel(
    const float* __restrict__ x,               // [32768, 1024]
    const int* __restrict__ mask,              // [32768]
    const unsigned short* __restrict__ wt,     // ws: bf16 Wt chunks [16][128][64]
    const float* __restrict__ bias,            // [128]
    const float* __restrict__ lb,              // [128]
    const float* __restrict__ rb,              // [128]
    float* __restrict__ out)                   // [32768, 128]
{
    __shared__ unsigned short lA[32 * LDA];    // 4352 B
    __shared__ unsigned short lB[128 * LDB];   // 17408 B

    const int tid  = threadIdx.x;
    const int wave = tid >> 6;
    const int lane = tid & 63;
    const int q    = lane >> 4;                // 0..3
    const int r    = lane & 15;                // 0..15

    const int mt   = wave >> 1;                // 16-row half
    const int nh   = wave & 1;                 // 64-col half
    const int row0 = blockIdx.x * 32;

    // --- staging assignments (coalesced) ---
    // A: thread c -> row ma = c>>3, float group ka = c&7 (8 floats = 32 B)
    const int ma = tid >> 3, ka = tid & 7;
    const float* __restrict__ xsrc = x + (size_t)(row0 + ma) * DD + ka * 8;
    // B: thread c -> row nb = c>>1, half hb = c&1 (32 bf16 = 64 B = 4 uint4)
    const int nb = tid >> 1, hb = tid & 1;
    const unsigned short* __restrict__ wsrc = wt + nb * 64 + hb * 32;
    unsigned short* const lAdst = &lA[ma * LDA + ka * 8];
    unsigned short* const lBdst = &lB[nb * LDB + hb * 32];

    f32x4 acc[4];
#pragma unroll
    for (int nt = 0; nt < 4; ++nt) acc[nt] = (f32x4){0.f, 0.f, 0.f, 0.f};

    // ping-pong prefetch registers
    float4 apf[2][2];
    uint4  bpf[2][4];

    // prefetch chunk 0
    apf[0][0] = *(const float4*)(xsrc);
    apf[0][1] = *(const float4*)(xsrc + 4);
#pragma unroll
    for (int u = 0; u < 4; ++u) bpf[0][u] = *(const uint4*)(wsrc + u * 8);

#pragma unroll
    for (int kc = 0; kc < NCHUNK; ++kc) {
        const int cur = kc & 1, nxt = cur ^ 1;

        // ---- stage prefetched regs into LDS (vmcnt wait lands here)
        {
            union { unsigned short s[8]; uint4 v; } pk;
            pk.s[0] = f2bf(apf[cur][0].x); pk.s[1] = f2bf(apf[cur][0].y);
            pk.s[2] = f2bf(apf[cur][0].z); pk.s[3] = f2bf(apf[cur][0].w);
            pk.s[4] = f2bf(apf[cur][1].x); pk.s[5] = f2bf(apf[cur][1].y);
            pk.s[6] = f2bf(apf[cur][1].z); pk.s[7] = f2bf(apf[cur][1].w);
            *(uint4*)lAdst = pk.v;
        }
#pragma unroll
        for (int u = 0; u < 4; ++u) *(uint4*)(lBdst + u * 8) = bpf[cur][u];
        __syncthreads();

        // ---- issue next chunk's global loads (consumed after NEXT barrier)
        if (kc < NCHUNK - 1) {
            const float* xs = xsrc + (kc + 1) * BK;
            apf[nxt][0] = *(const float4*)(xs);
            apf[nxt][1] = *(const float4*)(xs + 4);
            const unsigned short* ws = wsrc + (size_t)(kc + 1) * 8192;
#pragma unroll
            for (int u = 0; u < 4; ++u) bpf[nxt][u] = *(const uint4*)(ws + u * 8);
        }

        // ---- frag reads + MFMA on current LDS tile
#pragma unroll
        for (int ks = 0; ks < 2; ++ks) {
            short8 a = *(const short8*)(&lA[(mt * 16 + r) * LDA + ks * 32 + q * 8]);
            short8 b[4];
#pragma unroll
            for (int nt = 0; nt < 4; ++nt)
                b[nt] = *(const short8*)(&lB[(nh * 64 + nt * 16 + r) * LDB + ks * 32 + q * 8]);
#pragma unroll
            for (int nt = 0; nt < 4; ++nt)
                acc[nt] = __builtin_amdgcn_mfma_f32_16x16x32_bf16(a, b[nt], acc[nt], 0, 0, 0);
        }
        __syncthreads();
    }

    // ---- epilogue: bias + boundary masks.  C/D: col=lane&15 (N), row=q*4+reg (M).
#pragma unroll
    for (int reg = 0; reg < 4; ++reg) {
        const int m = row0 + mt * 16 + q * 4 + reg;
        const int t = m & (TT - 1);
        const int cur  = mask[m];
        const int prev = (t != 0)      ? mask[m - 1] : 0;
        const int nxt  = (t != TT - 1) ? mask[m + 1] : 0;
        const float sm = (cur > prev) ? 1.f : 0.f;   // start_mask
        const float em = (nxt > cur)  ? 1.f : 0.f;   // end_mask
#pragma unroll
        for (int nt = 0; nt < 4; ++nt) {
            const int n = nh * 64 + nt * 16 + r;
            float e = acc[nt][reg] + bias[n] + sm * lb[n] + em * rb[n];
            out[(size_t)m * UU + n] = e;
        }
    }
}

extern "C" void kernel_launch(void* const* d_in, const int* in_sizes, int n_in,
                              void* d_out, int out_size, void* d_ws, size_t ws_size,
                              hipStream_t stream) {
    const float* x    = (const float*)d_in[0];
    const int*   mask = (const int*)d_in[1];
    const float* w    = (const float*)d_in[2];
    const float* bias = (const float*)d_in[3];
    const float* lb   = (const float*)d_in[4];
    const float* rb   = (const float*)d_in[5];
    float* out = (float*)d_out;
    unsigned short* wt = (unsigned short*)d_ws;   // 256 KiB bf16 Wt

    wprep_kernel<<<64, 256, 0, stream>>>(w, wt);
    // 1024 blocks * 4 waves = 16 waves/CU, 4 independent barrier groups/CU
    crf_energy_kernel<<<1024, 256, 0, stream>>>(x, mask, wt, bias, lb, rb, out);
}

// Round 4
// 214.796 us; speedup vs baseline: 1.3197x; 1.3197x over previous
//
#include <hip/hip_runtime.h>

// Problem constants (reference: B=64, T=512, D=1024, U=128)
#define TT 512
#define DD 1024
#define UU 128
#define MM 32768            // B*T rows
#define BK 64
#define NCHUNK 16

typedef short short8 __attribute__((ext_vector_type(8)));   // 8 bf16 (MFMA A/B frag)
typedef float f32x4 __attribute__((ext_vector_type(4)));    // MFMA C/D frag

// fp32 -> bf16 round-to-nearest-even
__device__ __forceinline__ unsigned short f2bf(float f) {
    union { float f; unsigned u; } v; v.f = f;
    unsigned u = v.u;
    return (unsigned short)((u + 0x7fffu + ((u >> 16) & 1u)) >> 16);
}

// async global -> LDS DMA, 16 B/lane. LDS dst = wave-uniform base + lane*16.
__device__ __forceinline__ void glds16(const void* g, void* l) {
    __builtin_amdgcn_global_load_lds(
        (const __attribute__((address_space(1))) void*)g,
        (__attribute__((address_space(3))) void*)l, 16, 0, 0);
}

// ---------------------------------------------------------------------------
// Kernel 0: W[k][n] fp32 (1024x128) -> ws bf16, transposed+chunked:
// wt[kc*8192 + n*64 + k'] = bf16(W[kc*64+k'][n]).   (verified R1-R3)
// ---------------------------------------------------------------------------
__global__ __launch_bounds__(256) void wprep_kernel(const float* __restrict__ w,
                                                    unsigned short* __restrict__ wt) {
    int tg = blockIdx.x * 256 + threadIdx.x;   // 0..16383
    int kg = tg & 7;
    int n  = (tg >> 3) & 127;
    int kc = tg >> 10;
    union { unsigned short s[8]; uint4 v; } o;
#pragma unroll
    for (int j = 0; j < 8; ++j) {
        int k = kc * 64 + kg * 8 + j;
        o.s[j] = f2bf(w[k * 128 + n]);
    }
    *(uint4*)(wt + tg * 8) = o.v;
}

// ---------------------------------------------------------------------------
// Kernel 1: 32(M) x 128(N) per block, 4 waves, each wave 16x64.
// global_load_lds staging (A as fp32, B as bf16), XOR-swizzled LDS layouts,
// cvt-at-frag-read.  m97 2-barrier K-loop.  1024 blocks = 4 blocks/CU.
//
// LDS A: 32 rows x 16 groups(16B).  slot(m, g') holds global group g = g'^(m&15).
// LDS B: 128 rows x 8 groups(16B).  slot(n, g') holds global group g = g'^(n&7).
// ---------------------------------------------------------------------------
__global__ __launch_bounds__(256, 4) void crf_energy_kernel(
    const float* __restrict__ x,               // [32768, 1024]
    const int* __restrict__ mask,              // [32768]
    const unsigned short* __restrict__ wt,     // ws: bf16 Wt chunks [16][128][64]
    const float* __restrict__ bias,            // [128]
    const float* __restrict__ lb,              // [128]
    const float* __restrict__ rb,              // [128]
    float* __restrict__ out)                   // [32768, 128]
{
    __shared__ float lAf[32 * 64];             // 8 KiB  (fp32 A chunk)
    __shared__ unsigned short lBs[128 * 64];   // 16 KiB (bf16 B chunk)

    const int tid  = threadIdx.x;
    const int w    = tid >> 6;                 // wave 0..3
    const int lane = tid & 63;
    const int q    = lane >> 4;                // 0..3
    const int r    = lane & 15;                // 0..15

    const int mt   = w >> 1;                   // 16-row half (compute role)
    const int nh   = w & 1;                    // 64-col half
    const int row0 = blockIdx.x * 32;

    // ---- staging source addresses (swizzle applied on the GLOBAL side) ----
    // A: wave w stages rows [w*8, w*8+8), instr j in {0,1}:
    //    lane slot -> m = w*8 + j*4 + (lane>>4), g' = lane&15, g = g'^(m&15)
    int a_m[2], a_g[2];
#pragma unroll
    for (int j = 0; j < 2; ++j) {
        a_m[j] = w * 8 + j * 4 + (lane >> 4);
        a_g[j] = (lane & 15) ^ (a_m[j] & 15);
    }
    // B: wave w stages rows [w*32, w*32+32), instr j in {0..3}:
    //    n = w*32 + j*8 + (lane>>3), g' = lane&7, g = g'^(n&7)
    int b_n[4], b_g[4];
#pragma unroll
    for (int j = 0; j < 4; ++j) {
        b_n[j] = w * 32 + j * 8 + (lane >> 3);
        b_g[j] = (lane & 7) ^ (b_n[j] & 7);
    }
    char* const lA_base = (char*)lAf + w * 2048;   // +j*1024
    char* const lB_base = (char*)lBs + w * 4096;   // +j*1024

    f32x4 acc[4];
#pragma unroll
    for (int nt = 0; nt < 4; ++nt) acc[nt] = (f32x4){0.f, 0.f, 0.f, 0.f};

    for (int kc = 0; kc < NCHUNK; ++kc) {
        // ---- issue async staging for this chunk (no VGPR round-trip)
#pragma unroll
        for (int j = 0; j < 2; ++j)
            glds16(x + (size_t)(row0 + a_m[j]) * DD + kc * BK + a_g[j] * 4,
                   lA_base + j * 1024);
#pragma unroll
        for (int j = 0; j < 4; ++j)
            glds16(wt + (size_t)kc * 8192 + b_n[j] * 64 + b_g[j] * 8,
                   lB_base + j * 1024);
        __syncthreads();                       // vmcnt drain + barrier: LDS ready

        // ---- frag reads (swizzled addresses), cvt A, MFMA
#pragma unroll
        for (int ks = 0; ks < 2; ++ks) {
            const int m  = mt * 16 + r;
            const int g0 = ks * 8 + q * 2;     // even
            const float4 lo = *(const float4*)(&lAf[m * 64 + ((g0     ^ (m & 15)) * 4)]);
            const float4 hi = *(const float4*)(&lAf[m * 64 + (((g0+1) ^ (m & 15)) * 4)]);
            union { unsigned short s[8]; short8 v; } pk;
            pk.s[0] = f2bf(lo.x); pk.s[1] = f2bf(lo.y);
            pk.s[2] = f2bf(lo.z); pk.s[3] = f2bf(lo.w);
            pk.s[4] = f2bf(hi.x); pk.s[5] = f2bf(hi.y);
            pk.s[6] = f2bf(hi.z); pk.s[7] = f2bf(hi.w);
            const short8 a = pk.v;

            short8 b[4];
            const int gb = ks * 4 + q;
#pragma unroll
            for (int nt = 0; nt < 4; ++nt) {
                const int n = nh * 64 + nt * 16 + r;
                b[nt] = *(const short8*)(&lBs[n * 64 + ((gb ^ (n & 7)) * 8)]);
            }
#pragma unroll
            for (int nt = 0; nt < 4; ++nt)
                acc[nt] = __builtin_amdgcn_mfma_f32_16x16x32_bf16(a, b[nt], acc[nt], 0, 0, 0);
        }
        __syncthreads();                       // reads done before next overwrite
    }

    // ---- epilogue: bias + boundary masks.  C/D: col=lane&15 (N), row=q*4+reg (M).
#pragma unroll
    for (int reg = 0; reg < 4; ++reg) {
        const int m = row0 + mt * 16 + q * 4 + reg;
        const int t = m & (TT - 1);
        const int cur  = mask[m];
        const int prev = (t != 0)      ? mask[m - 1] : 0;
        const int nxt  = (t != TT - 1) ? mask[m + 1] : 0;
        const float sm = (cur > prev) ? 1.f : 0.f;   // start_mask
        const float em = (nxt > cur)  ? 1.f : 0.f;   // end_mask
#pragma unroll
        for (int nt = 0; nt < 4; ++nt) {
            const int n = nh * 64 + nt * 16 + r;
            float e = acc[nt][reg] + bias[n] + sm * lb[n] + em * rb[n];
            out[(size_t)m * UU + n] = e;
        }
    }
}

extern "C" void kernel_launch(void* const* d_in, const int* in_sizes, int n_in,
                              void* d_out, int out_size, void* d_ws, size_t ws_size,
                              hipStream_t stream) {
    const float* x    = (const float*)d_in[0];
    const int*   mask = (const int*)d_in[1];
    const float* w    = (const float*)d_in[2];
    const float* bias = (const float*)d_in[3];
    const float* lb   = (const float*)d_in[4];
    const float* rb   = (const float*)d_in[5];
    float* out = (float*)d_out;
    unsigned short* wt = (unsigned short*)d_ws;   // 256 KiB bf16 Wt

    wprep_kernel<<<64, 256, 0, stream>>>(w, wt);
    // 1024 blocks * 4 waves = 16 waves/CU, 4 independent barrier groups/CU
    crf_energy_kernel<<<1024, 256, 0, stream>>>(x, mask, wt, bias, lb, rb, out);
}

// Round 5
// 214.556 us; speedup vs baseline: 1.3212x; 1.0011x over previous
//
#include <hip/hip_runtime.h>

// Problem constants (reference: B=64, T=512, D=1024, U=128)
#define TT 512
#define DD 1024
#define UU 128
#define MM 32768            // B*T rows
#define BK 64
#define NCHUNK 16

typedef short short8 __attribute__((ext_vector_type(8)));   // 8 bf16 (MFMA A/B frag)
typedef float f32x4 __attribute__((ext_vector_type(4)));    // MFMA C/D frag

// fp32 -> bf16 round-to-nearest-even
__device__ __forceinline__ unsigned short f2bf(float f) {
    union { float f; unsigned u; } v; v.f = f;
    unsigned u = v.u;
    return (unsigned short)((u + 0x7fffu + ((u >> 16) & 1u)) >> 16);
}

// async global -> LDS DMA, 16 B/lane. LDS dst = wave-uniform base + lane*16.
__device__ __forceinline__ void glds16(const void* g, void* l) {
    __builtin_amdgcn_global_load_lds(
        (const __attribute__((address_space(1))) void*)g,
        (__attribute__((address_space(3))) void*)l, 16, 0, 0);
}

// ---------------------------------------------------------------------------
// Kernel 0: W[k][n] fp32 (1024x128) -> ws bf16, transposed+chunked:
// wt[kc*8192 + n*64 + k'] = bf16(W[kc*64+k'][n]).   (verified R1-R4)
// ---------------------------------------------------------------------------
__global__ __launch_bounds__(256) void wprep_kernel(const float* __restrict__ w,
                                                    unsigned short* __restrict__ wt) {
    int tg = blockIdx.x * 256 + threadIdx.x;   // 0..16383
    int kg = tg & 7;
    int n  = (tg >> 3) & 127;
    int kc = tg >> 10;
    union { unsigned short s[8]; uint4 v; } o;
#pragma unroll
    for (int j = 0; j < 8; ++j) {
        int k = kc * 64 + kg * 8 + j;
        o.s[j] = f2bf(w[k * 128 + n]);
    }
    *(uint4*)(wt + tg * 8) = o.v;
}

// ---------------------------------------------------------------------------
// Kernel 1: 64(M) x 128(N) per block, 4 waves, each wave 32x64 (2x4 accs).
// Double-buffered global_load_lds (A fp32, B bf16), XOR-swizzled LDS,
// ONE barrier per K-chunk: issue k+1 -> compute k -> syncthreads.
// 512 blocks = 2 blocks/CU, 64 KB LDS (both resident).
//
// LDS A: 64 rows x 16 groups(16B).  slot(m,g') holds global group g = g'^(m&15).
// LDS B: 128 rows x 8 groups(16B).  slot(n,g') holds global group g = g'^(n&7).
// ---------------------------------------------------------------------------
__global__ __launch_bounds__(256, 2) void crf_energy_kernel(
    const float* __restrict__ x,               // [32768, 1024]
    const int* __restrict__ mask,              // [32768]
    const unsigned short* __restrict__ wt,     // ws: bf16 Wt chunks [16][128][64]
    const float* __restrict__ bias,            // [128]
    const float* __restrict__ lb,              // [128]
    const float* __restrict__ rb,              // [128]
    float* __restrict__ out)                   // [32768, 128]
{
    __shared__ float lAf[2][64 * 64];          // 2 x 16 KiB (fp32 A chunk)
    __shared__ unsigned short lBs[2][128 * 64];// 2 x 16 KiB (bf16 B chunk)

    const int tid  = threadIdx.x;
    const int w    = tid >> 6;                 // wave 0..3
    const int lane = tid & 63;
    const int q    = lane >> 4;                // 0..3
    const int r    = lane & 15;                // 0..15

    const int mh   = w >> 1;                   // 32-row half (compute role)
    const int nh   = w & 1;                    // 64-col half
    const int row0 = blockIdx.x * 64;

    // ---- staging source indices (swizzle applied on the GLOBAL side) ----
    // A: wave w stages rows [w*16, w*16+16), instr j in {0..3}:
    //    m = w*16 + j*4 + (lane>>4), g' = lane&15, source group g = g'^(m&15)
    int a_m[4], a_g[4];
#pragma unroll
    for (int j = 0; j < 4; ++j) {
        a_m[j] = w * 16 + j * 4 + (lane >> 4);
        a_g[j] = (lane & 15) ^ (a_m[j] & 15);
    }
    // B: wave w stages rows [w*32, w*32+32), instr j in {0..3}:
    //    n = w*32 + j*8 + (lane>>3), g' = lane&7, source group g = g'^(n&7)
    int b_n[4], b_g[4];
#pragma unroll
    for (int j = 0; j < 4; ++j) {
        b_n[j] = w * 32 + j * 8 + (lane >> 3);
        b_g[j] = (lane & 7) ^ (b_n[j] & 7);
    }

    f32x4 acc[2][4];
#pragma unroll
    for (int mt = 0; mt < 2; ++mt)
#pragma unroll
        for (int nt = 0; nt < 4; ++nt) acc[mt][nt] = (f32x4){0.f, 0.f, 0.f, 0.f};

    // ---- prologue: stage chunk 0 into buffer 0
#pragma unroll
    for (int j = 0; j < 4; ++j)
        glds16(x + (size_t)(row0 + a_m[j]) * DD + a_g[j] * 4,
               (char*)lAf[0] + w * 4096 + j * 1024);
#pragma unroll
    for (int j = 0; j < 4; ++j)
        glds16(wt + b_n[j] * 64 + b_g[j] * 8,
               (char*)lBs[0] + w * 4096 + j * 1024);
    __syncthreads();

    for (int kc = 0; kc < NCHUNK; ++kc) {
        const int cb = kc & 1;

        // ---- issue chunk kc+1 into the other buffer (prefetch)
        if (kc < NCHUNK - 1) {
            const int pb = cb ^ 1;
#pragma unroll
            for (int j = 0; j < 4; ++j)
                glds16(x + (size_t)(row0 + a_m[j]) * DD + (kc + 1) * BK + a_g[j] * 4,
                       (char*)lAf[pb] + w * 4096 + j * 1024);
#pragma unroll
            for (int j = 0; j < 4; ++j)
                glds16(wt + (size_t)(kc + 1) * 8192 + b_n[j] * 64 + b_g[j] * 8,
                       (char*)lBs[pb] + w * 4096 + j * 1024);
        }

        // ---- compute on current buffer
        const float* const lA = lAf[cb];
        const unsigned short* const lB = lBs[cb];
#pragma unroll
        for (int ks = 0; ks < 2; ++ks) {
            short8 a[2];
#pragma unroll
            for (int mt = 0; mt < 2; ++mt) {
                const int m  = mh * 32 + mt * 16 + r;
                const int g0 = ks * 8 + q * 2;     // even
                const float4 lo = *(const float4*)(&lA[m * 64 + (((g0    ) ^ (m & 15)) * 4)]);
                const float4 hi = *(const float4*)(&lA[m * 64 + (((g0 + 1) ^ (m & 15)) * 4)]);
                union { unsigned short s[8]; short8 v; } pk;
                pk.s[0] = f2bf(lo.x); pk.s[1] = f2bf(lo.y);
                pk.s[2] = f2bf(lo.z); pk.s[3] = f2bf(lo.w);
                pk.s[4] = f2bf(hi.x); pk.s[5] = f2bf(hi.y);
                pk.s[6] = f2bf(hi.z); pk.s[7] = f2bf(hi.w);
                a[mt] = pk.v;
            }
            short8 b[4];
            const int gb = ks * 4 + q;
#pragma unroll
            for (int nt = 0; nt < 4; ++nt) {
                const int n = nh * 64 + nt * 16 + r;
                b[nt] = *(const short8*)(&lB[n * 64 + ((gb ^ (n & 7)) * 8)]);
            }
#pragma unroll
            for (int mt = 0; mt < 2; ++mt)
#pragma unroll
                for (int nt = 0; nt < 4; ++nt)
                    acc[mt][nt] = __builtin_amdgcn_mfma_f32_16x16x32_bf16(
                        a[mt], b[nt], acc[mt][nt], 0, 0, 0);
        }

        // ---- one barrier: waits prefetch completion + read-completion of cb
        __syncthreads();
    }

    // ---- epilogue: bias + boundary masks.  C/D: col=lane&15 (N), row=q*4+reg (M).
#pragma unroll
    for (int mt = 0; mt < 2; ++mt) {
#pragma unroll
        for (int reg = 0; reg < 4; ++reg) {
            const int m = row0 + mh * 32 + mt * 16 + q * 4 + reg;
            const int t = m & (TT - 1);
            const int cur  = mask[m];
            const int prev = (t != 0)      ? mask[m - 1] : 0;
            const int nxt  = (t != TT - 1) ? mask[m + 1] : 0;
            const float sm = (cur > prev) ? 1.f : 0.f;   // start_mask
            const float em = (nxt > cur)  ? 1.f : 0.f;   // end_mask
#pragma unroll
            for (int nt = 0; nt < 4; ++nt) {
                const int n = nh * 64 + nt * 16 + r;
                float e = acc[mt][nt][reg] + bias[n] + sm * lb[n] + em * rb[n];
                out[(size_t)m * UU + n] = e;
            }
        }
    }
}

extern "C" void kernel_launch(void* const* d_in, const int* in_sizes, int n_in,
                              void* d_out, int out_size, void* d_ws, size_t ws_size,
                              hipStream_t stream) {
    const float* x    = (const float*)d_in[0];
    const int*   mask = (const int*)d_in[1];
    const float* w    = (const float*)d_in[2];
    const float* bias = (const float*)d_in[3];
    const float* lb   = (const float*)d_in[4];
    const float* rb   = (const float*)d_in[5];
    float* out = (float*)d_out;
    unsigned short* wt = (unsigned short*)d_ws;   // 256 KiB bf16 Wt

    wprep_kernel<<<64, 256, 0, stream>>>(w, wt);
    // 512 blocks * 64 KB LDS = exactly 2 resident blocks/CU, dbuf prefetch
    crf_energy_kernel<<<512, 256, 0, stream>>>(x, mask, wt, bias, lb, rb, out);
}